// Round 1
// baseline (1010.804 us; speedup 1.0000x reference)
//
#include <hip/hip_runtime.h>

// SparsTriangularUpdate on MI355X (gfx950).
// nnz=240000, C_IN=256, C_CH=128, K=12.
// Two-pass MFMA bf16 pipeline; bsum ([12,128]) reduced via LDS + global atomics.

#define NNZ   240000
#define ROWS  64
#define NBLK  (NNZ / ROWS)   // 3750

typedef __attribute__((ext_vector_type(8))) short bf16x8;
typedef __attribute__((ext_vector_type(4))) float f32x4;

__device__ __forceinline__ unsigned short f2bf(float f) {
  unsigned int u = __float_as_uint(f);
  u += 0x7fffu + ((u >> 16) & 1u);   // round-to-nearest-even
  return (unsigned short)(u >> 16);
}
__device__ __forceinline__ float bf2f(unsigned short h) {
  return __uint_as_float(((unsigned int)h) << 16);
}

// ---------------------------------------------------------------------------
// prep: fp32->bf16 weight conversion (+ gate/lin interleave for K1) + zero bsum
// Wcat layout: rows n in [0,512): s=n>>7 (wave), rr=n&127, half=rr>>6
//   (0=gate,1=lin), ch=(s&1)*64+(rr&63); s<2 -> {W_ga,W_la}, s>=2 -> {W_gb,W_lb}
// ---------------------------------------------------------------------------
__global__ __launch_bounds__(256) void prep_kernel(
    const float* __restrict__ Wga, const float* __restrict__ Wla,
    const float* __restrict__ Wgb, const float* __restrict__ Wlb,
    const float* __restrict__ Wgo, const float* __restrict__ Wlo,
    unsigned short* __restrict__ wcat, unsigned short* __restrict__ wgo16,
    unsigned short* __restrict__ wlo16, float* __restrict__ bsum)
{
  const int tid = blockIdx.x * 256 + threadIdx.x;
  if (tid < 12 * 128) bsum[tid] = 0.f;
  if (tid < 131072) {                 // Wcat: 512 x 256
    const int n = tid >> 8, k = tid & 255;
    const int s = n >> 7, rr = n & 127, half = rr >> 6;
    const int ch = ((s & 1) << 6) + (rr & 63);
    const float* src = (s < 2) ? (half ? Wla : Wga) : (half ? Wlb : Wgb);
    wcat[tid] = f2bf(src[ch * 256 + k]);
  } else if (tid < 196608) {          // W_go: 256 x 256
    const int i = tid - 131072;
    wgo16[i] = f2bf(Wgo[i]);
  } else if (tid < 229376) {          // W_lo: 256 x 128
    const int i = tid - 196608;
    wlo16[i] = f2bf(Wlo[i]);
  }
}

// ---------------------------------------------------------------------------
// K1: LN(values) -> x (bf16, ws + LDS); X[64,256] @ Wcat^T (per-wave 64x128);
// gate; a -> ws; b -> LDS bsum -> global atomic bsum.
// Wave w covers n in [w*128, w*128+128): tiles 0..3 = gate rows, 4..7 = lin.
// ---------------------------------------------------------------------------
__global__ __launch_bounds__(256, 2) void k1_kernel(
    const float* __restrict__ values,
    const float* __restrict__ ln_g, const float* __restrict__ ln_b,
    const float* __restrict__ b_ga, const float* __restrict__ b_la,
    const float* __restrict__ b_gb, const float* __restrict__ b_lb,
    const unsigned short* __restrict__ wcat,
    unsigned short* __restrict__ x_ws,
    unsigned short* __restrict__ a_ws,
    float* __restrict__ bsum)
{
  __shared__ unsigned short x_lds[ROWS][264];   // stride 264: 16B-aligned rows
  __shared__ float bs_lds[12][128];
  const int tid = threadIdx.x;
  const int rbase = blockIdx.x * ROWS;

  for (int i = tid; i < 12 * 128; i += 256) (&bs_lds[0][0])[i] = 0.f;

  // ---- LayerNorm: 4 threads per row, 64 elements each ----
  {
    const int r = tid >> 2, j = tid & 3;
    const float4* vrow = (const float4*)(values + (size_t)(rbase + r) * 256 + j * 64);
    float4 v[16];
    float s1 = 0.f, s2 = 0.f;
#pragma unroll
    for (int i = 0; i < 16; i++) {
      const float4 t = vrow[i];
      v[i] = t;
      s1 += t.x + t.y + t.z + t.w;
      s2 += t.x * t.x + t.y * t.y + t.z * t.z + t.w * t.w;
    }
    s1 += __shfl_xor(s1, 1); s1 += __shfl_xor(s1, 2);
    s2 += __shfl_xor(s2, 1); s2 += __shfl_xor(s2, 2);
    const float mu = s1 * (1.f / 256.f);
    const float var = s2 * (1.f / 256.f) - mu * mu;
    const float rstd = rsqrtf(var + 1e-5f);
    const float4* g4 = (const float4*)(ln_g + j * 64);
    const float4* b4 = (const float4*)(ln_b + j * 64);
    ushort4* xg = (ushort4*)(x_ws + (size_t)(rbase + r) * 256 + j * 64);
#pragma unroll
    for (int i = 0; i < 16; i++) {
      const float4 gg = g4[i], bb = b4[i];
      ushort4 h;
      h.x = f2bf((v[i].x - mu) * rstd * gg.x + bb.x);
      h.y = f2bf((v[i].y - mu) * rstd * gg.y + bb.y);
      h.z = f2bf((v[i].z - mu) * rstd * gg.z + bb.z);
      h.w = f2bf((v[i].w - mu) * rstd * gg.w + bb.w);
      xg[i] = h;
      *(ushort4*)&x_lds[r][j * 64 + i * 4] = h;
    }
  }
  __syncthreads();

  // ---- MFMA: per wave, M=64 (4 tiles) x N=128 (8 tiles) x K=256 ----
  const int wv = tid >> 6;
  const int lane = tid & 63;
  const int m = lane & 15, q = lane >> 4;

  f32x4 acc[4][8];
#pragma unroll
  for (int a = 0; a < 4; a++)
#pragma unroll
    for (int b = 0; b < 8; b++) acc[a][b] = (f32x4){0.f, 0.f, 0.f, 0.f};

  const unsigned short* wp = wcat + ((wv * 128 + m) * 256 + q * 8);
#pragma unroll
  for (int kb = 0; kb < 8; kb++) {
    bf16x8 A[4];
#pragma unroll
    for (int mt = 0; mt < 4; mt++)
      A[mt] = *(const bf16x8*)&x_lds[mt * 16 + m][kb * 32 + q * 8];
#pragma unroll
    for (int t = 0; t < 8; t++) {
      const bf16x8 B = *(const bf16x8*)(wp + t * 16 * 256 + kb * 32);
#pragma unroll
      for (int mt = 0; mt < 4; mt++)
        acc[mt][t] = __builtin_amdgcn_mfma_f32_16x16x32_bf16(A[mt], B, acc[mt][t], 0, 0, 0);
    }
  }

  // ---- epilogue: sigmoid gate; a -> global, b -> LDS bsum ----
  const bool isA = (wv < 2);
  const int chbase = (wv & 1) * 64;
  const float* bgp = isA ? b_ga : b_gb;
  const float* blp = isA ? b_la : b_lb;
#pragma unroll
  for (int t = 0; t < 4; t++) {
    const int ch = chbase + t * 16 + m;
    const float bgv = bgp[ch], blv = blp[ch];
#pragma unroll
    for (int mt = 0; mt < 4; mt++) {
#pragma unroll
      for (int rg = 0; rg < 4; rg++) {
        const int lrow = mt * 16 + q * 4 + rg;
        const float gv = acc[mt][t][rg] + bgv;
        const float lv = acc[mt][t + 4][rg] + blv;
        const float val = lv / (1.f + __expf(-gv));
        if (isA) {
          a_ws[(size_t)(rbase + lrow) * 128 + ch] = f2bf(val);
        } else {
          atomicAdd(&bs_lds[(rbase + lrow) % 12][ch], val);
        }
      }
    }
  }
  __syncthreads();
  for (int i = tid; i < 12 * 128; i += 256)
    atomicAdd(&bsum[i], (&bs_lds[0][0])[i]);
}

// ---------------------------------------------------------------------------
// K2: tri = a * bsum[row%12] -> LN(128) -> t_lds (bf16);
// out = sigmoid(X @ Wgo^T + b_go) * (T @ Wlo^T + b_lo). Per-wave N=64.
// ---------------------------------------------------------------------------
__global__ __launch_bounds__(256, 2) void k2_kernel(
    const unsigned short* __restrict__ x_ws,
    const unsigned short* __restrict__ a_ws,
    const float* __restrict__ bsum,
    const float* __restrict__ ln_g, const float* __restrict__ ln_b,
    const unsigned short* __restrict__ wgo,
    const unsigned short* __restrict__ wlo,
    const float* __restrict__ b_go, const float* __restrict__ b_lo,
    float* __restrict__ out)
{
  __shared__ unsigned short t_lds[ROWS][136];
  const int tid = threadIdx.x;
  const int rbase = blockIdx.x * ROWS;

  // ---- tri + LN: 4 threads per row, 32 channels each ----
  {
    const int r = tid >> 2, j = tid & 3;
    const int row = rbase + r;
    const int k12 = row % 12;
    const float* bsrow = bsum + k12 * 128 + j * 32;    // 6KB, L1-resident
    const ushort4* ar = (const ushort4*)(a_ws + (size_t)row * 128 + j * 32);
    float tv[32];
    float s1 = 0.f, s2 = 0.f;
#pragma unroll
    for (int i = 0; i < 8; i++) {
      const ushort4 a4 = ar[i];
      const float t0 = bf2f(a4.x) * bsrow[i * 4 + 0];
      const float t1 = bf2f(a4.y) * bsrow[i * 4 + 1];
      const float t2 = bf2f(a4.z) * bsrow[i * 4 + 2];
      const float t3 = bf2f(a4.w) * bsrow[i * 4 + 3];
      tv[i * 4 + 0] = t0; tv[i * 4 + 1] = t1; tv[i * 4 + 2] = t2; tv[i * 4 + 3] = t3;
      s1 += t0 + t1 + t2 + t3;
      s2 += t0 * t0 + t1 * t1 + t2 * t2 + t3 * t3;
    }
    s1 += __shfl_xor(s1, 1); s1 += __shfl_xor(s1, 2);
    s2 += __shfl_xor(s2, 1); s2 += __shfl_xor(s2, 2);
    const float mu = s1 * (1.f / 128.f);
    const float rstd = rsqrtf(s2 * (1.f / 128.f) - mu * mu + 1e-5f);
    const float4* g4 = (const float4*)(ln_g + j * 32);
    const float4* b4 = (const float4*)(ln_b + j * 32);
#pragma unroll
    for (int i = 0; i < 8; i++) {
      const float4 gg = g4[i], bb = b4[i];
      ushort4 h;
      h.x = f2bf((tv[i * 4 + 0] - mu) * rstd * gg.x + bb.x);
      h.y = f2bf((tv[i * 4 + 1] - mu) * rstd * gg.y + bb.y);
      h.z = f2bf((tv[i * 4 + 2] - mu) * rstd * gg.z + bb.z);
      h.w = f2bf((tv[i * 4 + 3] - mu) * rstd * gg.w + bb.w);
      *(ushort4*)&t_lds[r][j * 32 + i * 4] = h;
    }
  }
  __syncthreads();

  const int wv = tid >> 6, lane = tid & 63;
  const int m = lane & 15, q = lane >> 4;

  f32x4 ag[4][4], al[4][4];
#pragma unroll
  for (int a = 0; a < 4; a++)
#pragma unroll
    for (int b = 0; b < 4; b++) { ag[a][b] = (f32x4){0.f,0.f,0.f,0.f}; al[a][b] = (f32x4){0.f,0.f,0.f,0.f}; }

  // gate GEMM: X[64,256] @ Wgo^T, A-frags straight from global bf16 x
  const unsigned short* wgp = wgo + ((wv * 64 + m) * 256 + q * 8);
  const unsigned short* xp = x_ws + (size_t)(rbase + m) * 256 + q * 8;
#pragma unroll
  for (int kb = 0; kb < 8; kb++) {
    bf16x8 A[4];
#pragma unroll
    for (int mt = 0; mt < 4; mt++)
      A[mt] = *(const bf16x8*)(xp + (size_t)mt * 16 * 256 + kb * 32);
#pragma unroll
    for (int nt = 0; nt < 4; nt++) {
      const bf16x8 B = *(const bf16x8*)(wgp + nt * 16 * 256 + kb * 32);
#pragma unroll
      for (int mt = 0; mt < 4; mt++)
        ag[mt][nt] = __builtin_amdgcn_mfma_f32_16x16x32_bf16(A[mt], B, ag[mt][nt], 0, 0, 0);
    }
  }
  // lin GEMM: T[64,128] @ Wlo^T, A-frags from LDS
  const unsigned short* wlp = wlo + ((wv * 64 + m) * 128 + q * 8);
#pragma unroll
  for (int kb = 0; kb < 4; kb++) {
    bf16x8 A[4];
#pragma unroll
    for (int mt = 0; mt < 4; mt++)
      A[mt] = *(const bf16x8*)&t_lds[mt * 16 + m][kb * 32 + q * 8];
#pragma unroll
    for (int nt = 0; nt < 4; nt++) {
      const bf16x8 B = *(const bf16x8*)(wlp + nt * 16 * 128 + kb * 32);
#pragma unroll
      for (int mt = 0; mt < 4; mt++)
        al[mt][nt] = __builtin_amdgcn_mfma_f32_16x16x32_bf16(A[mt], B, al[mt][nt], 0, 0, 0);
    }
  }

  // ---- epilogue ----
#pragma unroll
  for (int nt = 0; nt < 4; nt++) {
    const int n = wv * 64 + nt * 16 + m;
    const float bgo = b_go[n], blo = b_lo[n];
#pragma unroll
    for (int mt = 0; mt < 4; mt++) {
#pragma unroll
      for (int rg = 0; rg < 4; rg++) {
        const int row = rbase + mt * 16 + q * 4 + rg;
        const float gv = ag[mt][nt][rg] + bgo;
        const float lv = al[mt][nt][rg] + blo;
        out[(size_t)row * 256 + n] = lv / (1.f + __expf(-gv));
      }
    }
  }
}

// ---------------------------------------------------------------------------
extern "C" void kernel_launch(void* const* d_in, const int* in_sizes, int n_in,
                              void* d_out, int out_size, void* d_ws, size_t ws_size,
                              hipStream_t stream) {
  (void)in_sizes; (void)n_in; (void)out_size; (void)ws_size;
  const float* values  = (const float*)d_in[0];
  const float* ln_in_g = (const float*)d_in[1];
  const float* ln_in_b = (const float*)d_in[2];
  const float* W_ga = (const float*)d_in[3];
  const float* b_ga = (const float*)d_in[4];
  const float* W_la = (const float*)d_in[5];
  const float* b_la = (const float*)d_in[6];
  const float* W_gb = (const float*)d_in[7];
  const float* b_gb = (const float*)d_in[8];
  const float* W_lb = (const float*)d_in[9];
  const float* b_lb = (const float*)d_in[10];
  const float* ln_o_g = (const float*)d_in[11];
  const float* ln_o_b = (const float*)d_in[12];
  const float* W_go = (const float*)d_in[13];
  const float* b_go = (const float*)d_in[14];
  const float* W_lo = (const float*)d_in[15];
  const float* b_lo = (const float*)d_in[16];
  // d_in[17] = indices: unused by the reference.

  // workspace layout (184,784,896 bytes total, all offsets 256B-aligned)
  char* ws = (char*)d_ws;
  unsigned short* x_ws  = (unsigned short*)(ws + 0);          // 240000*256*2
  unsigned short* a_ws  = (unsigned short*)(ws + 122880000);  // 240000*128*2
  unsigned short* wcat  = (unsigned short*)(ws + 184320000);  // 512*256*2
  unsigned short* wgo16 = (unsigned short*)(ws + 184582144);  // 256*256*2
  unsigned short* wlo16 = (unsigned short*)(ws + 184713216);  // 256*128*2
  float*          bsum  = (float*)        (ws + 184778752);   // 12*128*4

  hipLaunchKernelGGL(prep_kernel, dim3(896), dim3(256), 0, stream,
                     W_ga, W_la, W_gb, W_lb, W_go, W_lo, wcat, wgo16, wlo16, bsum);
  hipLaunchKernelGGL(k1_kernel, dim3(NBLK), dim3(256), 0, stream,
                     values, ln_in_g, ln_in_b, b_ga, b_la, b_gb, b_lb,
                     wcat, x_ws, a_ws, bsum);
  hipLaunchKernelGGL(k2_kernel, dim3(NBLK), dim3(256), 0, stream,
                     x_ws, a_ws, bsum, ln_o_g, ln_o_b, wgo16, wlo16, b_go, b_lo,
                     (float*)d_out);
}

// Round 2
// 952.754 us; speedup vs baseline: 1.0609x; 1.0609x over previous
//
#include <hip/hip_runtime.h>

// SparsTriangularUpdate on MI355X (gfx950).
// nnz=240000, C_IN=256, C_CH=128, K=12.
// Two-pass MFMA bf16 pipeline. R2: 512-thr blocks / 64-reg acc tiles for
// 16 waves/CU; bsum via 32-slot striped partials + tiny reduce kernel.

#define NNZ   240000
#define ROWS  64
#define NBLK  (NNZ / ROWS)   // 3750
#define PSLOTS 32

typedef __attribute__((ext_vector_type(8))) short bf16x8;
typedef __attribute__((ext_vector_type(4))) float f32x4;

__device__ __forceinline__ unsigned short f2bf(float f) {
  unsigned int u = __float_as_uint(f);
  u += 0x7fffu + ((u >> 16) & 1u);   // round-to-nearest-even
  return (unsigned short)(u >> 16);
}
__device__ __forceinline__ float bf2f(unsigned short h) {
  return __uint_as_float(((unsigned int)h) << 16);
}

// ---------------------------------------------------------------------------
// prep: fp32->bf16 weights (+ K1 interleave) + zero bsum & partials.
// Wcat row n in [0,512): w=n>>6, t=(n>>4)&3, m=n&15; ch=(w&3)*32+(t&1)*16+m;
//   w<4 -> {t<2 ? W_ga : W_la}, w>=4 -> {t<2 ? W_gb : W_lb}
// ---------------------------------------------------------------------------
__global__ __launch_bounds__(256) void prep_kernel(
    const float* __restrict__ Wga, const float* __restrict__ Wla,
    const float* __restrict__ Wgb, const float* __restrict__ Wlb,
    const float* __restrict__ Wgo, const float* __restrict__ Wlo,
    unsigned short* __restrict__ wcat, unsigned short* __restrict__ wgo16,
    unsigned short* __restrict__ wlo16, float* __restrict__ bsum,
    float* __restrict__ bpart)
{
  const int tid = blockIdx.x * 256 + threadIdx.x;
  if (tid < 12 * 128) bsum[tid] = 0.f;
  if (tid < PSLOTS * 1536) bpart[tid] = 0.f;
  if (tid < 131072) {                 // Wcat: 512 x 256
    const int n = tid >> 8, k = tid & 255;
    const int w = n >> 6, t = (n >> 4) & 3, m = n & 15;
    const int ch = ((w & 3) << 5) + ((t & 1) << 4) + m;
    const float* src = (w < 4) ? (t < 2 ? Wga : Wla) : (t < 2 ? Wgb : Wlb);
    wcat[tid] = f2bf(src[ch * 256 + k]);
  } else if (tid < 196608) {          // W_go: 256 x 256
    const int i = tid - 131072;
    wgo16[i] = f2bf(Wgo[i]);
  } else if (tid < 229376) {          // W_lo: 256 x 128
    const int i = tid - 196608;
    wlo16[i] = f2bf(Wlo[i]);
  }
}

// ---------------------------------------------------------------------------
// K1: LN(values) -> x (bf16, ws + LDS); per-wave 64x64 MFMA vs Wcat;
// gate; a -> ws; b -> LDS bsum -> striped global partial (atomic, slot blk&31)
// ---------------------------------------------------------------------------
__global__ __launch_bounds__(512, 4) void k1_kernel(
    const float* __restrict__ values,
    const float* __restrict__ ln_g, const float* __restrict__ ln_b,
    const float* __restrict__ b_ga, const float* __restrict__ b_la,
    const float* __restrict__ b_gb, const float* __restrict__ b_lb,
    const unsigned short* __restrict__ wcat,
    unsigned short* __restrict__ x_ws,
    unsigned short* __restrict__ a_ws,
    float* __restrict__ bpart)
{
  __shared__ unsigned short x_lds[ROWS][264];   // stride 264 = 33*16B
  __shared__ float bs_lds[12][128];
  const int tid = threadIdx.x;
  const int rbase = blockIdx.x * ROWS;

  for (int i = tid; i < 12 * 128; i += 512) (&bs_lds[0][0])[i] = 0.f;

  // ---- LayerNorm: 8 threads per row, 32 elements each ----
  {
    const int r = tid >> 3, j = tid & 7;
    const float4* vrow = (const float4*)(values + (size_t)(rbase + r) * 256 + j * 32);
    float4 v[8];
    float s1 = 0.f, s2 = 0.f;
#pragma unroll
    for (int i = 0; i < 8; i++) {
      const float4 t = vrow[i];
      v[i] = t;
      s1 += t.x + t.y + t.z + t.w;
      s2 += t.x * t.x + t.y * t.y + t.z * t.z + t.w * t.w;
    }
    s1 += __shfl_xor(s1, 1); s1 += __shfl_xor(s1, 2); s1 += __shfl_xor(s1, 4);
    s2 += __shfl_xor(s2, 1); s2 += __shfl_xor(s2, 2); s2 += __shfl_xor(s2, 4);
    const float mu = s1 * (1.f / 256.f);
    const float rstd = rsqrtf(s2 * (1.f / 256.f) - mu * mu + 1e-5f);
    const float4* g4 = (const float4*)(ln_g + j * 32);
    const float4* b4 = (const float4*)(ln_b + j * 32);
    unsigned short* xg = x_ws + (size_t)(rbase + r) * 256 + j * 32;
#pragma unroll
    for (int i = 0; i < 4; i++) {
      const float4 a0 = v[2 * i], a1 = v[2 * i + 1];
      const float4 g0 = g4[2 * i], g1 = g4[2 * i + 1];
      const float4 c0 = b4[2 * i], c1 = b4[2 * i + 1];
      bf16x8 h;
      h[0] = (short)f2bf((a0.x - mu) * rstd * g0.x + c0.x);
      h[1] = (short)f2bf((a0.y - mu) * rstd * g0.y + c0.y);
      h[2] = (short)f2bf((a0.z - mu) * rstd * g0.z + c0.z);
      h[3] = (short)f2bf((a0.w - mu) * rstd * g0.w + c0.w);
      h[4] = (short)f2bf((a1.x - mu) * rstd * g1.x + c1.x);
      h[5] = (short)f2bf((a1.y - mu) * rstd * g1.y + c1.y);
      h[6] = (short)f2bf((a1.z - mu) * rstd * g1.z + c1.z);
      h[7] = (short)f2bf((a1.w - mu) * rstd * g1.w + c1.w);
      *(bf16x8*)(xg + i * 8) = h;
      *(bf16x8*)&x_lds[r][j * 32 + i * 8] = h;
    }
  }
  __syncthreads();

  // ---- MFMA: wave wv owns 64 rows x 64 Wcat rows (4 N-tiles), K=256 ----
  const int wv = tid >> 6;             // 0..7
  const int lane = tid & 63;
  const int m = lane & 15, q = lane >> 4;

  f32x4 acc[4][4];
#pragma unroll
  for (int a = 0; a < 4; a++)
#pragma unroll
    for (int b = 0; b < 4; b++) acc[a][b] = (f32x4){0.f, 0.f, 0.f, 0.f};

  const unsigned short* wp = wcat + ((wv * 64 + m) * 256 + q * 8);
#pragma unroll
  for (int kb = 0; kb < 8; kb++) {
    bf16x8 A[4];
#pragma unroll
    for (int mt = 0; mt < 4; mt++)
      A[mt] = *(const bf16x8*)&x_lds[mt * 16 + m][kb * 32 + q * 8];
#pragma unroll
    for (int t = 0; t < 4; t++) {
      const bf16x8 B = *(const bf16x8*)(wp + t * 16 * 256 + kb * 32);
#pragma unroll
      for (int mt = 0; mt < 4; mt++)
        acc[mt][t] = __builtin_amdgcn_mfma_f32_16x16x32_bf16(A[mt], B, acc[mt][t], 0, 0, 0);
    }
  }

  // ---- epilogue: tiles 0,1 = gate, 2,3 = lin; a -> global, b -> LDS bsum ----
  const bool isA = (wv < 4);
  const int chbase = (wv & 3) * 32;
  const float* bgp = isA ? b_ga : b_gb;
  const float* blp = isA ? b_la : b_lb;
#pragma unroll
  for (int t = 0; t < 2; t++) {
    const int ch = chbase + t * 16 + m;
    const float bgv = bgp[ch], blv = blp[ch];
#pragma unroll
    for (int mt = 0; mt < 4; mt++) {
#pragma unroll
      for (int rg = 0; rg < 4; rg++) {
        const int lrow = mt * 16 + q * 4 + rg;
        const float gv = acc[mt][t][rg] + bgv;
        const float lv = acc[mt][t + 2][rg] + blv;
        const float val = lv / (1.f + __expf(-gv));
        if (isA) {
          a_ws[(size_t)(rbase + lrow) * 128 + ch] = f2bf(val);
        } else {
          atomicAdd(&bs_lds[(rbase + lrow) % 12][ch], val);
        }
      }
    }
  }
  __syncthreads();
  float* dst = bpart + (blockIdx.x & (PSLOTS - 1)) * 1536;
  for (int i = tid; i < 1536; i += 512)
    atomicAdd(&dst[i], (&bs_lds[0][0])[i]);
}

// ---------------------------------------------------------------------------
// reduce: bsum[c] = sum over 32 slots of bpart
// ---------------------------------------------------------------------------
__global__ __launch_bounds__(256) void reduce_kernel(
    const float* __restrict__ bpart, float* __restrict__ bsum)
{
  const int c = blockIdx.x * 256 + threadIdx.x;   // grid 6 -> 1536 threads
  float s = 0.f;
#pragma unroll
  for (int sl = 0; sl < PSLOTS; sl++) s += bpart[sl * 1536 + c];
  bsum[c] = s;
}

// ---------------------------------------------------------------------------
// K2: tri = a * bsum[row%12] -> LN(128) -> t_lds; per-wave 64x32 (gate+lin);
// out = sigmoid(X @ Wgo^T + b_go) * (T @ Wlo^T + b_lo)
// ---------------------------------------------------------------------------
__global__ __launch_bounds__(512, 4) void k2_kernel(
    const unsigned short* __restrict__ x_ws,
    const unsigned short* __restrict__ a_ws,
    const float* __restrict__ bsum,
    const float* __restrict__ ln_g, const float* __restrict__ ln_b,
    const unsigned short* __restrict__ wgo,
    const unsigned short* __restrict__ wlo,
    const float* __restrict__ b_go, const float* __restrict__ b_lo,
    float* __restrict__ out)
{
  __shared__ unsigned short t_lds[ROWS][136];   // stride 136 = 17*16B
  const int tid = threadIdx.x;
  const int rbase = blockIdx.x * ROWS;

  // ---- tri + LN: 8 threads per row, 16 channels each ----
  {
    const int r = tid >> 3, j = tid & 7;
    const int row = rbase + r;
    const int k12 = row % 12;
    const float4* bs4 = (const float4*)(bsum + k12 * 128 + j * 16);
    const ushort4* ar = (const ushort4*)(a_ws + (size_t)row * 128 + j * 16);
    float tv[16];
    float s1 = 0.f, s2 = 0.f;
#pragma unroll
    for (int i = 0; i < 4; i++) {
      const ushort4 a4 = ar[i];
      const float4 bsv = bs4[i];
      const float t0 = bf2f(a4.x) * bsv.x;
      const float t1 = bf2f(a4.y) * bsv.y;
      const float t2 = bf2f(a4.z) * bsv.z;
      const float t3 = bf2f(a4.w) * bsv.w;
      tv[i * 4 + 0] = t0; tv[i * 4 + 1] = t1; tv[i * 4 + 2] = t2; tv[i * 4 + 3] = t3;
      s1 += t0 + t1 + t2 + t3;
      s2 += t0 * t0 + t1 * t1 + t2 * t2 + t3 * t3;
    }
    s1 += __shfl_xor(s1, 1); s1 += __shfl_xor(s1, 2); s1 += __shfl_xor(s1, 4);
    s2 += __shfl_xor(s2, 1); s2 += __shfl_xor(s2, 2); s2 += __shfl_xor(s2, 4);
    const float mu = s1 * (1.f / 128.f);
    const float rstd = rsqrtf(s2 * (1.f / 128.f) - mu * mu + 1e-5f);
    const float4* g4 = (const float4*)(ln_g + j * 16);
    const float4* b4 = (const float4*)(ln_b + j * 16);
#pragma unroll
    for (int i = 0; i < 2; i++) {
      const float4 g0 = g4[2 * i], g1 = g4[2 * i + 1];
      const float4 c0 = b4[2 * i], c1 = b4[2 * i + 1];
      bf16x8 h;
      h[0] = (short)f2bf((tv[8 * i + 0] - mu) * rstd * g0.x + c0.x);
      h[1] = (short)f2bf((tv[8 * i + 1] - mu) * rstd * g0.y + c0.y);
      h[2] = (short)f2bf((tv[8 * i + 2] - mu) * rstd * g0.z + c0.z);
      h[3] = (short)f2bf((tv[8 * i + 3] - mu) * rstd * g0.w + c0.w);
      h[4] = (short)f2bf((tv[8 * i + 4] - mu) * rstd * g1.x + c1.x);
      h[5] = (short)f2bf((tv[8 * i + 5] - mu) * rstd * g1.y + c1.y);
      h[6] = (short)f2bf((tv[8 * i + 6] - mu) * rstd * g1.z + c1.z);
      h[7] = (short)f2bf((tv[8 * i + 7] - mu) * rstd * g1.w + c1.w);
      *(bf16x8*)&t_lds[r][j * 16 + i * 8] = h;
    }
  }
  __syncthreads();

  const int wv = tid >> 6, lane = tid & 63;
  const int m = lane & 15, q = lane >> 4;

  f32x4 ag[4][2], al[4][2];
#pragma unroll
  for (int a = 0; a < 4; a++)
#pragma unroll
    for (int b = 0; b < 2; b++) { ag[a][b] = (f32x4){0.f,0.f,0.f,0.f}; al[a][b] = (f32x4){0.f,0.f,0.f,0.f}; }

  // gate GEMM: X[64,256] @ Wgo^T (32 out-chans per wave), A from global bf16 x
  const unsigned short* wgp = wgo + ((wv * 32 + m) * 256 + q * 8);
  const unsigned short* xp = x_ws + (size_t)(rbase + m) * 256 + q * 8;
#pragma unroll
  for (int kb = 0; kb < 8; kb++) {
    bf16x8 A[4];
#pragma unroll
    for (int mt = 0; mt < 4; mt++)
      A[mt] = *(const bf16x8*)(xp + (size_t)mt * 16 * 256 + kb * 32);
#pragma unroll
    for (int nt = 0; nt < 2; nt++) {
      const bf16x8 B = *(const bf16x8*)(wgp + nt * 16 * 256 + kb * 32);
#pragma unroll
      for (int mt = 0; mt < 4; mt++)
        ag[mt][nt] = __builtin_amdgcn_mfma_f32_16x16x32_bf16(A[mt], B, ag[mt][nt], 0, 0, 0);
    }
  }
  // lin GEMM: T[64,128] @ Wlo^T, A from LDS
  const unsigned short* wlp = wlo + ((wv * 32 + m) * 128 + q * 8);
#pragma unroll
  for (int kb = 0; kb < 4; kb++) {
    bf16x8 A[4];
#pragma unroll
    for (int mt = 0; mt < 4; mt++)
      A[mt] = *(const bf16x8*)&t_lds[mt * 16 + m][kb * 32 + q * 8];
#pragma unroll
    for (int nt = 0; nt < 2; nt++) {
      const bf16x8 B = *(const bf16x8*)(wlp + nt * 16 * 128 + kb * 32);
#pragma unroll
      for (int mt = 0; mt < 4; mt++)
        al[mt][nt] = __builtin_amdgcn_mfma_f32_16x16x32_bf16(A[mt], B, al[mt][nt], 0, 0, 0);
    }
  }

  // ---- epilogue ----
#pragma unroll
  for (int nt = 0; nt < 2; nt++) {
    const int n = wv * 32 + nt * 16 + m;
    const float bgo = b_go[n], blo = b_lo[n];
#pragma unroll
    for (int mt = 0; mt < 4; mt++) {
#pragma unroll
      for (int rg = 0; rg < 4; rg++) {
        const int row = rbase + mt * 16 + q * 4 + rg;
        const float gv = ag[mt][nt][rg] + bgo;
        const float lv = al[mt][nt][rg] + blo;
        out[(size_t)row * 256 + n] = lv / (1.f + __expf(-gv));
      }
    }
  }
}

// ---------------------------------------------------------------------------
extern "C" void kernel_launch(void* const* d_in, const int* in_sizes, int n_in,
                              void* d_out, int out_size, void* d_ws, size_t ws_size,
                              hipStream_t stream) {
  (void)in_sizes; (void)n_in; (void)out_size; (void)ws_size;
  const float* values  = (const float*)d_in[0];
  const float* ln_in_g = (const float*)d_in[1];
  const float* ln_in_b = (const float*)d_in[2];
  const float* W_ga = (const float*)d_in[3];
  const float* b_ga = (const float*)d_in[4];
  const float* W_la = (const float*)d_in[5];
  const float* b_la = (const float*)d_in[6];
  const float* W_gb = (const float*)d_in[7];
  const float* b_gb = (const float*)d_in[8];
  const float* W_lb = (const float*)d_in[9];
  const float* b_lb = (const float*)d_in[10];
  const float* ln_o_g = (const float*)d_in[11];
  const float* ln_o_b = (const float*)d_in[12];
  const float* W_go = (const float*)d_in[13];
  const float* b_go = (const float*)d_in[14];
  const float* W_lo = (const float*)d_in[15];
  const float* b_lo = (const float*)d_in[16];
  // d_in[17] = indices: unused by the reference.

  // workspace layout (184,981,504 bytes, all offsets 256B-aligned)
  char* ws = (char*)d_ws;
  unsigned short* x_ws  = (unsigned short*)(ws + 0);          // 240000*256*2
  unsigned short* a_ws  = (unsigned short*)(ws + 122880000);  // 240000*128*2
  unsigned short* wcat  = (unsigned short*)(ws + 184320000);  // 512*256*2
  unsigned short* wgo16 = (unsigned short*)(ws + 184582144);  // 256*256*2
  unsigned short* wlo16 = (unsigned short*)(ws + 184713216);  // 256*128*2
  float*          bsum  = (float*)        (ws + 184778752);   // 12*128*4
  float*          bpart = (float*)        (ws + 184784896);   // 32*1536*4

  hipLaunchKernelGGL(prep_kernel, dim3(896), dim3(256), 0, stream,
                     W_ga, W_la, W_gb, W_lb, W_go, W_lo, wcat, wgo16, wlo16,
                     bsum, bpart);
  hipLaunchKernelGGL(k1_kernel, dim3(NBLK), dim3(512), 0, stream,
                     values, ln_in_g, ln_in_b, b_ga, b_la, b_gb, b_lb,
                     wcat, x_ws, a_ws, bpart);
  hipLaunchKernelGGL(reduce_kernel, dim3(6), dim3(256), 0, stream,
                     bpart, bsum);
  hipLaunchKernelGGL(k2_kernel, dim3(NBLK), dim3(512), 0, stream,
                     x_ws, a_ws, bsum, ln_o_g, ln_o_b, wgo16, wlo16, b_go, b_lo,
                     (float*)d_out);
}